// Round 8
// baseline (177.665 us; speedup 1.0000x reference)
//
#include <hip/hip_runtime.h>
#include <stdint.h>

// Beam-search step for CaptionModel (B=128 beams, V=128000 vocab).
//
// Identity (verified bit-exact, rounds 2+4 absmax=0.0): reference's two-stage
// top-k == single global top-128 over (sum[b] + lp[b,v]) with composite key
// (f32key<<32) | (0xFFFFFFFF - (b*V+v)) reproducing jax's tie order.
//
// Structure (5 graph nodes; k_pick fused into k_main prologue):
//  memset   : zero shist (16KB) + cnt
//  k_sample : 1/16 systematic sample -> 4096-bin hist of top-12 key bits
//  k_main   : per-block prologue re-derives threshold bin from shist (~1us,
//             L2-broadcast), then ONE full 65.5MB nontemporal streaming pass;
//             candidates >= t_lo to per-block LDS buffer, 1 global atomic/block
//  k_select : exact top-128 of ~2-6K candidates (two-level radix refine +
//             bitonic sort of <=512 finalists)
//  k_scatter: gather/write outputs (float4 on state h/c)
//
// dur_us model (round-4 counters): harness restore+poison ~= 125us fixed
// (268MB 0xAA fill = 41us x N + 63MB input restore); our kernels ~20-30us.

#define SHIST 4096
#define CAP 32768
#define LCAP 1024
#define FINCAP 512

typedef unsigned long long u64;
typedef float f32x4 __attribute__((ext_vector_type(4)));

__device__ __forceinline__ unsigned f2key(float f) {
  unsigned u = __float_as_uint(f);
  return (u & 0x80000000u) ? ~u : (u | 0x80000000u);
}
__device__ __forceinline__ float key2f(unsigned k) {
  unsigned u = (k & 0x80000000u) ? (k & 0x7fffffffu) : ~k;
  return __uint_as_float(u);
}

// Parallel suffix-scan threshold over h[SHIST]: find bin such that
// count(bins > bin) < target <= count(bins >= bin). All 256 threads call.
__device__ __forceinline__ void suffix_thresh(unsigned* h /*SHIST*/, unsigned* seg /*256*/,
                                              unsigned target, int* sh_bin,
                                              unsigned* sh_above, int tid) {
  unsigned s = 0;
#pragma unroll
  for (int j = 0; j < SHIST / 256; ++j) s += h[tid * (SHIST / 256) + j];
  seg[tid] = s;
  __syncthreads();
  for (int off = 1; off < 256; off <<= 1) {   // inclusive suffix sums
    unsigned add = (tid + off < 256) ? seg[tid + off] : 0;
    __syncthreads();
    seg[tid] += add;
    __syncthreads();
  }
  unsigned excl = (tid + 1 < 256) ? seg[tid + 1] : 0;  // count above my segment
  unsigned incl = seg[tid];
  if (tid == 0) { *sh_bin = 0; *sh_above = 0; }        // default: total < target
  __syncthreads();
  if (excl < target && incl >= target) {               // unique crossing thread
    unsigned acc = excl;
    int lo = tid * (SHIST / 256);
    for (int bn = lo + SHIST / 256 - 1; bn >= lo; --bn) {
      unsigned hb = h[bn];
      if (acc + hb >= target) { *sh_bin = bn; *sh_above = acc; break; }
      acc += hb;
    }
  }
  __syncthreads();
}

extern "C" __global__ void __launch_bounds__(256)
k_sample(const float* __restrict__ logp, const float* __restrict__ bsum,
         const int* __restrict__ tptr, int V, int bs,
         unsigned* __restrict__ shist) {
  __shared__ unsigned hist[SHIST];
  for (int i = threadIdx.x; i < SHIST; i += 256) hist[i] = 0;
  __syncthreads();
  int t = *tptr;
  int rows = (t >= 1) ? bs : 1;
  long long total = (long long)rows * V;
  long long step = total / gridDim.x;           // systematic sample: chunk prefix
  long long start = (long long)blockIdx.x * step;
  int tid = threadIdx.x;
#pragma unroll 4
  for (int j = 0; j < 16; ++j) {                // 4096 elems per block, coalesced
    long long idx = start + (long long)j * 256 + tid;
    if (idx < total) {
      int b = (int)(idx / V);
      int v = (int)(idx - (long long)b * V);
      float x = logp[idx];
      if (v == V - 1) x -= 1000.0f;
      atomicAdd(&hist[f2key(bsum[b] + x) >> 20], 1u);
    }
  }
  __syncthreads();
  for (int i = tid; i < SHIST; i += 256) {
    unsigned c = hist[i];
    if (c) atomicAdd(&shist[i], c);
  }
}

extern "C" __global__ void __launch_bounds__(256)
k_main(const float* __restrict__ logp, const float* __restrict__ bsum,
       const int* __restrict__ tptr, int V, int bs,
       const unsigned* __restrict__ shist,
       u64* __restrict__ cand, int* __restrict__ cnt) {
  __shared__ unsigned hist[SHIST];
  __shared__ unsigned seg[256];
  __shared__ u64 lbuf[LCAP];
  __shared__ int lcnt, lbase, sh_bin;
  __shared__ unsigned sh_above;
  int tid = threadIdx.x;
  if (tid == 0) lcnt = 0;
  // prologue: derive threshold bin from global sample histogram (L2-hot)
  for (int i = tid; i < SHIST; i += 256) hist[i] = shist[i];
  __syncthreads();
  suffix_thresh(hist, seg, (unsigned)bs, &sh_bin, &sh_above, tid);
  unsigned tlo = (unsigned)sh_bin << 20;

  int t = *tptr;
  int rows = (t >= 1) ? bs : 1;
  if ((V & 3) == 0) {
    unsigned V4 = (unsigned)V >> 2;
    unsigned total4 = (unsigned)rows * V4;
    unsigned chunk = (total4 + gridDim.x - 1) / gridDim.x;  // contiguous per block
    unsigned start = blockIdx.x * chunk;
    unsigned end = start + chunk;
    if (end > total4) end = total4;
    const f32x4* lp4 = (const f32x4*)logp;
    for (unsigned i = start + tid; i < end; i += 256) {
      unsigned b = i / V4;
      unsigned v0 = (i - b * V4) << 2;
      f32x4 f = __builtin_nontemporal_load(&lp4[i]);
      float s = bsum[b];
      float xs[4] = {f.x, f.y, f.z, f.w};
      if (v0 + 3 == (unsigned)V - 1) xs[3] -= 1000.0f;   // EOS penalty
#pragma unroll
      for (int j = 0; j < 4; ++j) {
        unsigned key = f2key(s + xs[j]);
        if (key >= tlo) {
          int p = atomicAdd(&lcnt, 1);
          if (p < LCAP) {
            unsigned flat = b * (unsigned)V + v0 + j;
            lbuf[p] = ((u64)key << 32) | (0xFFFFFFFFu - flat);
          }
        }
      }
    }
  } else {
    long long total = (long long)rows * V;
    long long chunk = (total + gridDim.x - 1) / gridDim.x;
    long long start = (long long)blockIdx.x * chunk;
    long long end = start + chunk;
    if (end > total) end = total;
    for (long long i = start + tid; i < end; i += 256) {
      int b = (int)(i / V);
      int v = (int)(i - (long long)b * V);
      float x = logp[i];
      if (v == V - 1) x -= 1000.0f;
      unsigned key = f2key(bsum[b] + x);
      if (key >= tlo) {
        int p = atomicAdd(&lcnt, 1);
        if (p < LCAP) {
          unsigned flat = (unsigned)b * (unsigned)V + (unsigned)v;
          lbuf[p] = ((u64)key << 32) | (0xFFFFFFFFu - flat);
        }
      }
    }
  }
  __syncthreads();
  int n = lcnt < LCAP ? lcnt : LCAP;
  if (tid == 0) lbase = atomicAdd(cnt, n);
  __syncthreads();
  int base = lbase;
  for (int i = tid; i < n; i += 256) {
    int g = base + i;
    if (g < CAP) cand[g] = lbuf[i];
  }
}

extern "C" __global__ void __launch_bounds__(256)
k_select(const float* __restrict__ logp, const int* __restrict__ cntp,
         const u64* __restrict__ cand_g, int V, int K,
         float* __restrict__ out_sum, int* __restrict__ qsel,
         int* __restrict__ tok, float* __restrict__ loc) {
  __shared__ unsigned hist[SHIST];
  __shared__ unsigned seg[256];
  __shared__ u64 fin[FINCAP];
  __shared__ int sh_bin, sh_nfin;
  __shared__ unsigned sh_above;
  int tid = threadIdx.x;
  int n = *cntp;
  if (n > CAP) n = CAP;
  for (int i = tid; i < SHIST; i += 256) hist[i] = 0;
  if (tid == 0) sh_nfin = 0;
  __syncthreads();
  // level 1: top-12 key bits
  for (int i = tid; i < n; i += 256)
    atomicAdd(&hist[(unsigned)(cand_g[i] >> 52)], 1u);
  __syncthreads();
  suffix_thresh(hist, seg, (unsigned)K, &sh_bin, &sh_above, tid);
  int tbin = sh_bin;
  unsigned cnt_hi = sh_above;          // count with bin > tbin (< K)
  __syncthreads();
  // level 2: bits [19:8] within the tie bin
  for (int i = tid; i < SHIST; i += 256) hist[i] = 0;
  __syncthreads();
  for (int i = tid; i < n; i += 256) {
    unsigned key = (unsigned)(cand_g[i] >> 32);
    if ((int)(key >> 20) == tbin) atomicAdd(&hist[(key >> 8) & 0xFFFu], 1u);
  }
  __syncthreads();
  unsigned need = (unsigned)K - cnt_hi;
  suffix_thresh(hist, seg, need, &sh_bin, &sh_above, tid);
  int tbin2 = sh_bin;
  __syncthreads();
  // collect finalists
  for (int i = tid; i < n; i += 256) {
    u64 c = cand_g[i];
    unsigned key = (unsigned)(c >> 32);
    int bin = (int)(key >> 20);
    bool keep = (bin > tbin) || (bin == tbin && (int)((key >> 8) & 0xFFFu) >= tbin2);
    if (keep) {
      int p = atomicAdd(&sh_nfin, 1);
      if (p < FINCAP) fin[p] = c;
    }
  }
  __syncthreads();
  int nf = sh_nfin < FINCAP ? sh_nfin : FINCAP;
  int m = 2;
  while (m < nf) m <<= 1;              // power of two <= FINCAP
  for (int i = nf + tid; i < m; i += 256) fin[i] = 0ull;
  __syncthreads();
  for (int k2 = 2; k2 <= m; k2 <<= 1) {
    for (int j = k2 >> 1; j > 0; j >>= 1) {
      for (int i = tid; i < m; i += 256) {
        int l = i ^ j;
        if (l > i) {
          u64 ai = fin[i], al = fin[l];
          bool desc = ((i & k2) == 0);
          if (desc ? (ai < al) : (ai > al)) { fin[i] = al; fin[l] = ai; }
        }
      }
      __syncthreads();
    }
  }
  if (tid < K) {
    u64 c = fin[tid];
    unsigned key = (unsigned)(c >> 32);
    unsigned flat = 0xFFFFFFFFu - (unsigned)(c & 0xFFFFFFFFull);
    int b = (int)(flat / (unsigned)V);
    int v = (int)(flat - (unsigned)b * (unsigned)V);
    out_sum[tid] = key2f(key);         // bit-exact sum[b] + penalized lp
    qsel[tid] = b;
    tok[tid] = v;
    float x = logp[(size_t)b * V + v];
    if (v == V - 1) x -= 1000.0f;
    loc[tid] = x;                      // exact ys value
  }
}

extern "C" __global__ void __launch_bounds__(256)
k_scatter(const int* __restrict__ beam_seq, const float* __restrict__ beam_lp,
          const float4* __restrict__ h4, const float4* __restrict__ c4,
          const int* __restrict__ tptr, const int* __restrict__ qsel,
          const int* __restrict__ tok, const float* __restrict__ loc,
          int T, int B, int LBH4, int H4,
          float* __restrict__ out, float4* __restrict__ outh4,
          float4* __restrict__ outc4) {
  int t = *tptr;
  size_t n_seq = (size_t)T * B;
  size_t scalar_items = 2 * n_seq;
  size_t total = scalar_items + 2 * (size_t)LBH4;
  size_t stride = (size_t)gridDim.x * 256;
  for (size_t j = (size_t)blockIdx.x * 256 + threadIdx.x; j < total; j += stride) {
    if (j < n_seq) {
      int ss = (int)(j / B), b = (int)(j % B);
      int val;
      if (ss < t)       val = beam_seq[(size_t)ss * B + qsel[b]];
      else if (ss == t) val = tok[b];
      else              val = beam_seq[j];
      out[j] = (float)val;             // token ids < 2^24: exact in f32
    } else if (j < scalar_items) {
      size_t jj = j - n_seq;
      int ss = (int)(jj / B), b = (int)(jj % B);
      float v;
      if (ss < t)       v = beam_lp[(size_t)ss * B + qsel[b]];
      else if (ss == t) v = loc[b];
      else              v = beam_lp[jj];
      out[j] = v;
    } else {
      size_t jj = j - scalar_items;
      bool is_c = jj >= (size_t)LBH4;
      size_t k = is_c ? jj - (size_t)LBH4 : jj;
      int row = (int)(k / H4);
      int h = (int)(k - (size_t)row * H4);
      int b = row % B;                 // row = l*B + b
      size_t src = (size_t)(row - b + qsel[b]) * H4 + h;
      if (is_c) outc4[k] = c4[src];
      else      outh4[k] = h4[src];
    }
  }
}

extern "C" void kernel_launch(void* const* d_in, const int* in_sizes, int n_in,
                              void* d_out, int out_size, void* d_ws, size_t ws_size,
                              hipStream_t stream) {
  const float* logp = (const float*)d_in[0];
  const int* beam_seq = (const int*)d_in[1];
  const float* beam_lp = (const float*)d_in[2];
  const float* bsum = (const float*)d_in[3];
  const float* st_h = (const float*)d_in[4];
  const float* st_c = (const float*)d_in[5];
  const int* tptr = (const int*)d_in[6];

  int B = in_sizes[3];                 // 128
  int V = in_sizes[0] / B;             // 128000
  int T = in_sizes[1] / B;             // 128
  int LBH = in_sizes[4];               // L*B*H = 262144
  int LH = LBH / B;                    // L*H = 2048
  int bs = (out_size - 2 * in_sizes[1]) / (1 + 2 * LH);  // beam_size = 128
  int H = 1024;                        // fixed for this problem
  int H4 = H / 4, LBH4 = LBH / 4;

  char* ws = (char*)d_ws;
  unsigned* shist = (unsigned*)ws;                        // 16384 B
  int* cnt = (int*)(ws + 16384);                          // 4 B
  u64* cand = (u64*)(ws + 16392);                         // CAP*8 B (8-aligned)
  int* qsel = (int*)(ws + 16392 + CAP * 8);
  int* tok = qsel + bs;
  float* loc = (float*)(tok + bs);

  float* out = (float*)d_out;
  size_t n_seq = (size_t)T * B;
  float* out_sum = out + 2 * n_seq;
  float4* outh4 = (float4*)(out + 2 * n_seq + bs);        // 16B-aligned offset
  float4* outc4 = outh4 + LBH4;

  hipMemsetAsync(d_ws, 0, 16392, stream);
  k_sample<<<256, 256, 0, stream>>>(logp, bsum, tptr, V, bs, shist);
  k_main<<<2048, 256, 0, stream>>>(logp, bsum, tptr, V, bs, shist, cand, cnt);
  k_select<<<1, 256, 0, stream>>>(logp, cnt, cand, V, bs, out_sum, qsel, tok, loc);

  size_t total = 2 * n_seq + 2 * (size_t)LBH4;
  int blocks = (int)((total + 255) / 256);
  k_scatter<<<blocks, 256, 0, stream>>>(beam_seq, beam_lp,
                                        (const float4*)st_h, (const float4*)st_c,
                                        tptr, qsel, tok, loc,
                                        T, B, LBH4, H4, out, outh4, outc4);
}

// Round 14
// 157.503 us; speedup vs baseline: 1.1280x; 1.1280x over previous
//
#include <hip/hip_runtime.h>
#include <stdint.h>

// Beam-search step for CaptionModel (B=128 beams, V=128000 vocab).
//
// Identity (verified bit-exact, rounds 2/4/8 absmax=0.0): reference's
// two-stage top-k == single global top-128 over (sum[b] + lp[b,v]) with
// composite key (f32key<<32) | (0xFFFFFFFF - (b*V+v)) matching jax tie order.
//
// Structure (lesson from round-8 counters: keep the streaming kernel
// LEAN — no per-block prologue, no nt-hints, small LDS, grid-stride):
//  memset   : zero shist (16KB) + cnt
//  k_sample : 1/16 systematic sample -> 4096-bin hist of top-12 key bits (~3us)
//  k_pick   : ONE block derives threshold bin -> tlo key (~2us)
//  k_main   : full 65.5MB pass, grid-stride float4, plain loads (L3-friendly),
//             4KB LDS -> high occupancy; candidates to LDS buf, 1 atomic/blk
//  k_select : exact top-128 of ~2-6K candidates (two-level radix + bitonic)
//  k_scatter: gather/write outputs (float4 on state h/c)

#define SHIST 4096
#define CAP 32768
#define LCAP 512
#define FINCAP 512

typedef unsigned long long u64;

__device__ __forceinline__ unsigned f2key(float f) {
  unsigned u = __float_as_uint(f);
  return (u & 0x80000000u) ? ~u : (u | 0x80000000u);
}
__device__ __forceinline__ float key2f(unsigned k) {
  unsigned u = (k & 0x80000000u) ? (k & 0x7fffffffu) : ~k;
  return __uint_as_float(u);
}

// Parallel suffix-scan threshold over h[SHIST]: find bin such that
// count(bins > bin) < target <= count(bins >= bin). All 256 threads call.
__device__ __forceinline__ void suffix_thresh(unsigned* h /*SHIST*/, unsigned* seg /*256*/,
                                              unsigned target, int* sh_bin,
                                              unsigned* sh_above, int tid) {
  unsigned s = 0;
#pragma unroll
  for (int j = 0; j < SHIST / 256; ++j) s += h[tid * (SHIST / 256) + j];
  seg[tid] = s;
  __syncthreads();
  for (int off = 1; off < 256; off <<= 1) {   // inclusive suffix sums
    unsigned add = (tid + off < 256) ? seg[tid + off] : 0;
    __syncthreads();
    seg[tid] += add;
    __syncthreads();
  }
  unsigned excl = (tid + 1 < 256) ? seg[tid + 1] : 0;  // count above my segment
  unsigned incl = seg[tid];
  if (tid == 0) { *sh_bin = 0; *sh_above = 0; }        // default: total < target
  __syncthreads();
  if (excl < target && incl >= target) {               // unique crossing thread
    unsigned acc = excl;
    int lo = tid * (SHIST / 256);
    for (int bn = lo + SHIST / 256 - 1; bn >= lo; --bn) {
      unsigned hb = h[bn];
      if (acc + hb >= target) { *sh_bin = bn; *sh_above = acc; break; }
      acc += hb;
    }
  }
  __syncthreads();
}

extern "C" __global__ void __launch_bounds__(256)
k_sample(const float* __restrict__ logp, const float* __restrict__ bsum,
         const int* __restrict__ tptr, int V, int bs,
         unsigned* __restrict__ shist) {
  __shared__ unsigned hist[SHIST];
  for (int i = threadIdx.x; i < SHIST; i += 256) hist[i] = 0;
  __syncthreads();
  int t = *tptr;
  int rows = (t >= 1) ? bs : 1;
  long long total = (long long)rows * V;
  long long step = total / gridDim.x;           // systematic sample: chunk prefix
  long long start = (long long)blockIdx.x * step;
  int tid = threadIdx.x;
#pragma unroll 4
  for (int j = 0; j < 16; ++j) {                // 4096 elems per block, coalesced
    long long idx = start + (long long)j * 256 + tid;
    if (idx < total) {
      int b = (int)(idx / V);
      int v = (int)(idx - (long long)b * V);
      float x = logp[idx];
      if (v == V - 1) x -= 1000.0f;
      atomicAdd(&hist[f2key(bsum[b] + x) >> 20], 1u);
    }
  }
  __syncthreads();
  for (int i = tid; i < SHIST; i += 256) {
    unsigned c = hist[i];
    if (c) atomicAdd(&shist[i], c);
  }
}

extern "C" __global__ void __launch_bounds__(256)
k_pick(const unsigned* __restrict__ shist, int K, unsigned* __restrict__ tlo_key) {
  __shared__ unsigned h[SHIST];
  __shared__ unsigned seg[256];
  __shared__ int sh_bin;
  __shared__ unsigned sh_above;
  int tid = threadIdx.x;
  for (int i = tid; i < SHIST; i += 256) h[i] = shist[i];
  __syncthreads();
  suffix_thresh(h, seg, (unsigned)K, &sh_bin, &sh_above, tid);
  if (tid == 0) *tlo_key = (unsigned)sh_bin << 20;
}

extern "C" __global__ void __launch_bounds__(256)
k_main(const float* __restrict__ logp, const float* __restrict__ bsum,
       const int* __restrict__ tptr, int V, int bs,
       const unsigned* __restrict__ tlo_p,
       u64* __restrict__ cand, int* __restrict__ cnt) {
  __shared__ u64 lbuf[LCAP];
  __shared__ int lcnt, lbase;
  int tid = threadIdx.x;
  if (tid == 0) lcnt = 0;
  __syncthreads();
  int t = *tptr;
  int rows = (t >= 1) ? bs : 1;
  unsigned tlo = *tlo_p;
  if ((V & 3) == 0) {
    unsigned V4 = (unsigned)V >> 2;
    unsigned total4 = (unsigned)rows * V4;
    unsigned stride = gridDim.x * 256;
    const float4* lp4 = (const float4*)logp;
    for (unsigned i = blockIdx.x * 256 + tid; i < total4; i += stride) {
      unsigned b = i / V4;
      unsigned v0 = (i - b * V4) << 2;
      float4 f = lp4[i];
      float s = bsum[b];
      float xs[4] = {f.x, f.y, f.z, f.w};
      if (v0 + 3 == (unsigned)V - 1) xs[3] -= 1000.0f;   // EOS penalty
#pragma unroll
      for (int j = 0; j < 4; ++j) {
        unsigned key = f2key(s + xs[j]);
        if (key >= tlo) {
          int p = atomicAdd(&lcnt, 1);
          if (p < LCAP) {
            unsigned flat = b * (unsigned)V + v0 + j;
            lbuf[p] = ((u64)key << 32) | (0xFFFFFFFFu - flat);
          }
        }
      }
    }
  } else {
    long long total = (long long)rows * V;
    long long stride = (long long)gridDim.x * 256;
    for (long long i = (long long)blockIdx.x * 256 + tid; i < total; i += stride) {
      int b = (int)(i / V);
      int v = (int)(i - (long long)b * V);
      float x = logp[i];
      if (v == V - 1) x -= 1000.0f;
      unsigned key = f2key(bsum[b] + x);
      if (key >= tlo) {
        int p = atomicAdd(&lcnt, 1);
        if (p < LCAP) {
          unsigned flat = (unsigned)b * (unsigned)V + (unsigned)v;
          lbuf[p] = ((u64)key << 32) | (0xFFFFFFFFu - flat);
        }
      }
    }
  }
  __syncthreads();
  int n = lcnt < LCAP ? lcnt : LCAP;
  if (tid == 0) lbase = atomicAdd(cnt, n);
  __syncthreads();
  int base = lbase;
  for (int i = tid; i < n; i += 256) {
    int g = base + i;
    if (g < CAP) cand[g] = lbuf[i];
  }
}

extern "C" __global__ void __launch_bounds__(256)
k_select(const float* __restrict__ logp, const int* __restrict__ cntp,
         const u64* __restrict__ cand_g, int V, int K,
         float* __restrict__ out_sum, int* __restrict__ qsel,
         int* __restrict__ tok, float* __restrict__ loc) {
  __shared__ unsigned hist[SHIST];
  __shared__ unsigned seg[256];
  __shared__ u64 fin[FINCAP];
  __shared__ int sh_bin, sh_nfin;
  __shared__ unsigned sh_above;
  int tid = threadIdx.x;
  int n = *cntp;
  if (n > CAP) n = CAP;
  for (int i = tid; i < SHIST; i += 256) hist[i] = 0;
  if (tid == 0) sh_nfin = 0;
  __syncthreads();
  // level 1: top-12 key bits
  for (int i = tid; i < n; i += 256)
    atomicAdd(&hist[(unsigned)(cand_g[i] >> 52)], 1u);
  __syncthreads();
  suffix_thresh(hist, seg, (unsigned)K, &sh_bin, &sh_above, tid);
  int tbin = sh_bin;
  unsigned cnt_hi = sh_above;          // count with bin > tbin (< K)
  __syncthreads();
  // level 2: bits [19:8] within the tie bin
  for (int i = tid; i < SHIST; i += 256) hist[i] = 0;
  __syncthreads();
  for (int i = tid; i < n; i += 256) {
    unsigned key = (unsigned)(cand_g[i] >> 32);
    if ((int)(key >> 20) == tbin) atomicAdd(&hist[(key >> 8) & 0xFFFu], 1u);
  }
  __syncthreads();
  unsigned need = (unsigned)K - cnt_hi;
  suffix_thresh(hist, seg, need, &sh_bin, &sh_above, tid);
  int tbin2 = sh_bin;
  __syncthreads();
  // collect finalists
  for (int i = tid; i < n; i += 256) {
    u64 c = cand_g[i];
    unsigned key = (unsigned)(c >> 32);
    int bin = (int)(key >> 20);
    bool keep = (bin > tbin) || (bin == tbin && (int)((key >> 8) & 0xFFFu) >= tbin2);
    if (keep) {
      int p = atomicAdd(&sh_nfin, 1);
      if (p < FINCAP) fin[p] = c;
    }
  }
  __syncthreads();
  int nf = sh_nfin < FINCAP ? sh_nfin : FINCAP;
  int m = 2;
  while (m < nf) m <<= 1;              // power of two <= FINCAP
  for (int i = nf + tid; i < m; i += 256) fin[i] = 0ull;
  __syncthreads();
  for (int k2 = 2; k2 <= m; k2 <<= 1) {
    for (int j = k2 >> 1; j > 0; j >>= 1) {
      for (int i = tid; i < m; i += 256) {
        int l = i ^ j;
        if (l > i) {
          u64 ai = fin[i], al = fin[l];
          bool desc = ((i & k2) == 0);
          if (desc ? (ai < al) : (ai > al)) { fin[i] = al; fin[l] = ai; }
        }
      }
      __syncthreads();
    }
  }
  if (tid < K) {
    u64 c = fin[tid];
    unsigned key = (unsigned)(c >> 32);
    unsigned flat = 0xFFFFFFFFu - (unsigned)(c & 0xFFFFFFFFull);
    int b = (int)(flat / (unsigned)V);
    int v = (int)(flat - (unsigned)b * (unsigned)V);
    out_sum[tid] = key2f(key);         // bit-exact sum[b] + penalized lp
    qsel[tid] = b;
    tok[tid] = v;
    float x = logp[(size_t)b * V + v];
    if (v == V - 1) x -= 1000.0f;
    loc[tid] = x;                      // exact ys value
  }
}

extern "C" __global__ void __launch_bounds__(256)
k_scatter(const int* __restrict__ beam_seq, const float* __restrict__ beam_lp,
          const float4* __restrict__ h4, const float4* __restrict__ c4,
          const int* __restrict__ tptr, const int* __restrict__ qsel,
          const int* __restrict__ tok, const float* __restrict__ loc,
          int T, int B, int LBH4, int H4,
          float* __restrict__ out, float4* __restrict__ outh4,
          float4* __restrict__ outc4) {
  int t = *tptr;
  size_t n_seq = (size_t)T * B;
  size_t scalar_items = 2 * n_seq;
  size_t total = scalar_items + 2 * (size_t)LBH4;
  size_t stride = (size_t)gridDim.x * 256;
  for (size_t j = (size_t)blockIdx.x * 256 + threadIdx.x; j < total; j += stride) {
    if (j < n_seq) {
      int ss = (int)(j / B), b = (int)(j % B);
      int val;
      if (ss < t)       val = beam_seq[(size_t)ss * B + qsel[b]];
      else if (ss == t) val = tok[b];
      else              val = beam_seq[j];
      out[j] = (float)val;             // token ids < 2^24: exact in f32
    } else if (j < scalar_items) {
      size_t jj = j - n_seq;
      int ss = (int)(jj / B), b = (int)(jj % B);
      float v;
      if (ss < t)       v = beam_lp[(size_t)ss * B + qsel[b]];
      else if (ss == t) v = loc[b];
      else              v = beam_lp[jj];
      out[j] = v;
    } else {
      size_t jj = j - scalar_items;
      bool is_c = jj >= (size_t)LBH4;
      size_t k = is_c ? jj - (size_t)LBH4 : jj;
      int row = (int)(k / H4);
      int h = (int)(k - (size_t)row * H4);
      int b = row % B;                 // row = l*B + b
      size_t src = (size_t)(row - b + qsel[b]) * H4 + h;
      if (is_c) outc4[k] = c4[src];
      else      outh4[k] = h4[src];
    }
  }
}

extern "C" void kernel_launch(void* const* d_in, const int* in_sizes, int n_in,
                              void* d_out, int out_size, void* d_ws, size_t ws_size,
                              hipStream_t stream) {
  const float* logp = (const float*)d_in[0];
  const int* beam_seq = (const int*)d_in[1];
  const float* beam_lp = (const float*)d_in[2];
  const float* bsum = (const float*)d_in[3];
  const float* st_h = (const float*)d_in[4];
  const float* st_c = (const float*)d_in[5];
  const int* tptr = (const int*)d_in[6];

  int B = in_sizes[3];                 // 128
  int V = in_sizes[0] / B;             // 128000
  int T = in_sizes[1] / B;             // 128
  int LBH = in_sizes[4];               // L*B*H = 262144
  int LH = LBH / B;                    // L*H = 2048
  int bs = (out_size - 2 * in_sizes[1]) / (1 + 2 * LH);  // beam_size = 128
  int H = 1024;                        // fixed for this problem
  int H4 = H / 4, LBH4 = LBH / 4;

  char* ws = (char*)d_ws;
  unsigned* shist = (unsigned*)ws;                        // 16384 B
  int* cnt = (int*)(ws + 16384);                          // 4 B
  unsigned* tlo_key = (unsigned*)(ws + 16388);            // 4 B
  u64* cand = (u64*)(ws + 16392);                         // CAP*8 B (8-aligned)
  int* qsel = (int*)(ws + 16392 + CAP * 8);
  int* tok = qsel + bs;
  float* loc = (float*)(tok + bs);

  float* out = (float*)d_out;
  size_t n_seq = (size_t)T * B;
  float* out_sum = out + 2 * n_seq;
  float4* outh4 = (float4*)(out + 2 * n_seq + bs);        // 16B-aligned offset
  float4* outc4 = outh4 + LBH4;

  hipMemsetAsync(d_ws, 0, 16392, stream);
  k_sample<<<256, 256, 0, stream>>>(logp, bsum, tptr, V, bs, shist);
  k_pick<<<1, 256, 0, stream>>>(shist, bs, tlo_key);
  k_main<<<1024, 256, 0, stream>>>(logp, bsum, tptr, V, bs, tlo_key, cand, cnt);
  k_select<<<1, 256, 0, stream>>>(logp, cnt, cand, V, bs, out_sum, qsel, tok, loc);

  size_t total = 2 * n_seq + 2 * (size_t)LBH4;
  int blocks = (int)((total + 255) / 256);
  k_scatter<<<blocks, 256, 0, stream>>>(beam_seq, beam_lp,
                                        (const float4*)st_h, (const float4*)st_c,
                                        tptr, qsel, tok, loc,
                                        T, B, LBH4, H4, out, outh4, outc4);
}